// Round 1
// 621.045 us; speedup vs baseline: 1.0429x; 1.0429x over previous
//
#include <hip/hip_runtime.h>
#include <cstdint>
#include <cstddef>

#define AS1 __attribute__((address_space(1)))
#define AS3 __attribute__((address_space(3)))

typedef __attribute__((ext_vector_type(4))) float f32x4;
typedef __attribute__((ext_vector_type(16))) float f32x16;
typedef __attribute__((ext_vector_type(4))) int i32x4;
typedef __attribute__((ext_vector_type(8))) int i32x8;

constexpr int HD = 4096;   // hidden dim (= K = out dim)
constexpr float FP8MAX = 448.0f;

// ---------------- fp8 pack ----------------
__device__ inline uint32_t pack4_fp8(float a, float b, float c, float d) {
    int v = 0;
    v = __builtin_amdgcn_cvt_pk_fp8_f32(a, b, v, false);  // low word
    v = __builtin_amdgcn_cvt_pk_fp8_f32(c, d, v, true);   // high word
    return (uint32_t)v;
}

__device__ inline float clipmul(float y, float rcs) {
    float t = y * rcs;                     // rcs = 1/s (one IEEE div upstream)
    t = fminf(t, FP8MAX);
    t = fmaxf(t, -FP8MAX);
    return t;
}

__device__ inline uint32_t quant4(float4 v, float rcs) {
    return pack4_fp8(clipmul(v.x, rcs), clipmul(v.y, rcs),
                     clipmul(v.z, rcs), clipmul(v.w, rcs));
}

// ---------------- weight absmax (per tensor, blockIdx.z selects W) ----------------
__global__ __launch_bounds__(256) void w_absmax(const float* __restrict__ W0,
                                                const float* __restrict__ W1,
                                                const float* __restrict__ W2,
                                                uint32_t* __restrict__ wmax) {
    __shared__ float red[4];
    const float* W = (blockIdx.z == 0) ? W0 : (blockIdx.z == 1 ? W1 : W2);
    const float4* W4 = (const float4*)W;
    const int n4 = HD * HD / 4;
    float m = 0.f;
    for (int i = blockIdx.x * blockDim.x + threadIdx.x; i < n4; i += gridDim.x * blockDim.x) {
        float4 v = W4[i];
        m = fmaxf(m, fmaxf(fmaxf(fabsf(v.x), fabsf(v.y)), fmaxf(fabsf(v.z), fabsf(v.w))));
    }
#pragma unroll
    for (int i = 32; i > 0; i >>= 1) m = fmaxf(m, __shfl_xor(m, i, 64));
    if ((threadIdx.x & 63) == 0) red[threadIdx.x >> 6] = m;
    __syncthreads();
    if (threadIdx.x == 0) {
        m = fmaxf(fmaxf(red[0], red[1]), fmaxf(red[2], red[3]));
        atomicMax((unsigned int*)(wmax + blockIdx.z), __float_as_uint(m));
    }
}

// ---------------- standalone weight quantize (fallback path only) ----------------
__global__ __launch_bounds__(256) void w_quant(const float* __restrict__ W,
                                               const uint32_t* __restrict__ wmaxbits,
                                               uint32_t* __restrict__ qw) {
    const float rsw = 1.0f / fmaxf(__uint_as_float(*wmaxbits) / FP8MAX, 1e-12f);
    const int i = blockIdx.x * blockDim.x + threadIdx.x;
    qw[i] = quant4(((const float4*)W)[i], rsw);
}

// ---------------- fused (relu|add) + rmsnorm + (quant | final write) [+ W quant] ----------------
// Blocks [0,4096): row work.  Blocks [4096, 8192) (when launched): quantize Wq -> qwout.
// mode 0: v = relu(xin); store resid; quant
// mode 1: v = xin + addin; store resid; quant
// mode 2: v = xin + addin; write y to yout (final), no resid/quant
__global__ __launch_bounds__(256) void fused_rms(const float* __restrict__ xin,
                                                 const float* __restrict__ addin,
                                                 float* __restrict__ resid_out,
                                                 const float* __restrict__ nw,
                                                 uint32_t* __restrict__ qx,
                                                 float* __restrict__ srow,
                                                 float* __restrict__ yout,
                                                 const int mode,
                                                 const float* __restrict__ Wq,
                                                 const uint32_t* __restrict__ wqmaxbits,
                                                 uint32_t* __restrict__ qwout) {
    const int tid = threadIdx.x;
    if (blockIdx.x >= 4096) {
        // ---- merged weight-quant blocks ----
        const float rsw = 1.0f / fmaxf(__uint_as_float(*wqmaxbits) / FP8MAX, 1e-12f);
        const float4* W4 = (const float4*)Wq;
        int i = (blockIdx.x - 4096) * 256 + tid;
#pragma unroll
        for (int it = 0; it < 4; it++, i += 4096 * 256)
            qwout[i] = quant4(W4[i], rsw);
        return;
    }

    __shared__ float reds[4];
    __shared__ float redm[4];
    const int row = blockIdx.x;
    const size_t base = (size_t)row * HD;
    const float4* xr = (const float4*)(xin + base);
    const float4* nw4 = (const float4*)nw;

    float4 v[4], w[4];
    float ss = 0.f, pm = 0.f;
    if (mode == 0) {
#pragma unroll
        for (int j = 0; j < 4; j++) {
            float4 t = xr[tid + j * 256];
            w[j] = nw4[tid + j * 256];
            t.x = fmaxf(t.x, 0.f); t.y = fmaxf(t.y, 0.f);
            t.z = fmaxf(t.z, 0.f); t.w = fmaxf(t.w, 0.f);
            v[j] = t;
            ss += t.x * t.x + t.y * t.y + t.z * t.z + t.w * t.w;
            pm = fmaxf(pm, fmaxf(fmaxf(fabsf(t.x * w[j].x), fabsf(t.y * w[j].y)),
                                 fmaxf(fabsf(t.z * w[j].z), fabsf(t.w * w[j].w))));
        }
    } else {
        const float4* ar = (const float4*)(addin + base);
#pragma unroll
        for (int j = 0; j < 4; j++) {
            float4 t = xr[tid + j * 256];
            float4 a = ar[tid + j * 256];
            w[j] = nw4[tid + j * 256];
            t.x += a.x; t.y += a.y; t.z += a.z; t.w += a.w;
            v[j] = t;
            ss += t.x * t.x + t.y * t.y + t.z * t.z + t.w * t.w;
            pm = fmaxf(pm, fmaxf(fmaxf(fabsf(t.x * w[j].x), fabsf(t.y * w[j].y)),
                                 fmaxf(fabsf(t.z * w[j].z), fabsf(t.w * w[j].w))));
        }
    }
    if (resid_out) {
        float4* ro = (float4*)(resid_out + base);
#pragma unroll
        for (int j = 0; j < 4; j++) ro[tid + j * 256] = v[j];
    }

    // combined block reduction (one barrier phase)
#pragma unroll
    for (int i = 32; i > 0; i >>= 1) {
        ss += __shfl_xor(ss, i, 64);
        pm = fmaxf(pm, __shfl_xor(pm, i, 64));
    }
    if ((tid & 63) == 0) { reds[tid >> 6] = ss; redm[tid >> 6] = pm; }
    __syncthreads();
    ss = (reds[0] + reds[1]) + (reds[2] + reds[3]);
    pm = fmaxf(fmaxf(redm[0], redm[1]), fmaxf(redm[2], redm[3]));

    const float rs = 1.0f / sqrtf(ss / (float)HD + 1e-6f);

    if (mode == 2) {
        float4* yo = (float4*)(yout + base);
#pragma unroll
        for (int j = 0; j < 4; j++) {
            float4 t;
            t.x = (v[j].x * rs) * w[j].x; t.y = (v[j].y * rs) * w[j].y;
            t.z = (v[j].z * rs) * w[j].z; t.w = (v[j].w * rs) * w[j].w;
            yo[tid + j * 256] = t;
        }
        return;
    }

    const float amax = pm * rs;
    const float s = fmaxf(amax / FP8MAX, 1e-12f);
    const float rcs = 1.0f / s;
    if (tid == 0) srow[row] = s;
    uint32_t* qr = qx + base / 4;
#pragma unroll
    for (int j = 0; j < 4; j++) {
        float4 t;
        t.x = (v[j].x * rs) * w[j].x; t.y = (v[j].y * rs) * w[j].y;
        t.z = (v[j].z * rs) * w[j].z; t.w = (v[j].w * rs) * w[j].w;
        qr[tid + j * 256] = quant4(t, rcs);
    }
}

// ---------------- MX-scaled fp8 GEMM, 256x256 tile, 8-phase counted-vmcnt schedule ----------------
// out[m][n] = (sum_k qx[m][k]*qw[n][k]) * srow[m] * ws
// BM=BN=256, BK=128, 512 threads = 8 waves (2M x 4N); per-wave C = 128x64 = 4x2 tiles of 32x32.
// LDS 128 KiB: per buffer, per operand, two 16KB K-half arrays (s0 = K bytes [0,64), s1 = [64,128)),
// row stride 64 B, 16B-slot swizzle phys = kg ^ ((row>>1)&3) (inverse-swizzled global source, linear
// global_load_lds dest, swizzled ds_read).
// Schedule per K-tile: 4 phases {ds_read frags ; issue 1 stage unit (2 x global_load_lds) ; barrier ;
// setprio(1) 4x mfma_scale_32x32x64 setprio(0) ; [vmcnt(4) at phases 1,3] ; barrier}.
// vmcnt never drains to 0 in the main loop (T4). Last iteration wrap-stages k=0 (harmless) to keep
// the vmcnt ledger invariant without branches.
typedef union { i32x8 v8; i32x4 v4[2]; } frag8;

__global__ __launch_bounds__(512, 2) void gemm_fp8mx(const uint8_t* __restrict__ qx,
                                                     const uint8_t* __restrict__ qw,
                                                     const float* __restrict__ srow,
                                                     const uint32_t* __restrict__ wmaxbits,
                                                     float* __restrict__ out) {
    __shared__ i32x4 AsL[2][2][1024];   // [buf][khalf][row*4 + slot] : 64 KiB
    __shared__ i32x4 BsL[2][2][1024];   // 64 KiB

    const int tid = threadIdx.x;
    const int wave = tid >> 6, lane = tid & 63;
    const int lr = lane & 31, lh = lane >> 5;
    const int m0 = blockIdx.y * 256, n0 = blockIdx.x * 256;
    const int wm = (wave >> 2) * 128, wn = (wave & 3) * 64;

    // staging map: dest element = tid (16B each) -> logical (row = tid>>2, slot = tid&3);
    // source logical kg = slot ^ ((row>>1)&3)  (same swizzle for row and row+128 since 64%4==0)
    const int str = tid >> 2;
    const int skg = (tid & 3) ^ ((str >> 1) & 3);
    const size_t srcA = (size_t)(m0 + str) * HD + (size_t)(skg * 16);
    const size_t srcB = (size_t)(n0 + str) * HD + (size_t)(skg * 16);

    f32x16 acc[4][2];
#pragma unroll
    for (int i = 0; i < 4; i++)
#pragma unroll
        for (int j = 0; j < 2; j++)
#pragma unroll
            for (int e = 0; e < 16; e++) acc[i][j][e] = 0.f;

    frag8 af0, af1, af2, af3, bf0, bf1;

#define STAGE_U(gp, soff, larr, koff) do {                                              \
    __builtin_amdgcn_global_load_lds((const AS1 void*)((gp) + (soff) + (size_t)(koff)), \
                                     (AS3 void*)((larr) + tid), 16, 0, 0);              \
    __builtin_amdgcn_global_load_lds((const AS1 void*)((gp) + (soff) + (size_t)(koff) + 128u * HD), \
                                     (AS3 void*)((larr) + 512 + tid), 16, 0, 0);        \
} while (0)

#define READ_F(dst, rbase, larr) do {                 \
    const int r_ = (rbase);                           \
    const i32x4* p_ = (larr) + r_ * 4;                \
    const int sw_ = (r_ >> 1) & 3;                    \
    dst.v4[0] = p_[(lh * 2) ^ sw_];                   \
    dst.v4[1] = p_[(lh * 2 + 1) ^ sw_];               \
} while (0)

#define MFMA1(a_, b_, i_, j_)                                                            \
    acc[i_][j_] = __builtin_amdgcn_mfma_scale_f32_32x32x64_f8f6f4(                       \
        (a_).v8, (b_).v8, acc[i_][j_], 0, 0, 0, 0x7F7F7F7Fu, 0, 0x7F7F7F7Fu)

#define MFMA4(a0_, a1_, r0_, r1_) do {               \
    __builtin_amdgcn_s_setprio(1);                   \
    MFMA1(a0_, bf0, r0_, 0);                         \
    MFMA1(a0_, bf1, r0_, 1);                         \
    MFMA1(a1_, bf0, r1_, 0);                         \
    MFMA1(a1_, bf1, r1_, 1);                         \
    __builtin_amdgcn_s_setprio(0);                   \
} while (0)

#define KTILE(bR, bS, knext) do {                                   \
    /* p0: s0 frags rows 0-63, stage next A-s0 */                   \
    READ_F(af0, wm + lr,      &AsL[bR][0][0]);                      \
    READ_F(af1, wm + 32 + lr, &AsL[bR][0][0]);                      \
    READ_F(bf0, wn + lr,      &BsL[bR][0][0]);                      \
    READ_F(bf1, wn + 32 + lr, &BsL[bR][0][0]);                      \
    STAGE_U(qx, srcA, &AsL[bS][0][0], (knext));                     \
    __builtin_amdgcn_s_barrier();                                   \
    MFMA4(af0, af1, 0, 1);                                          \
    __builtin_amdgcn_s_barrier();                                   \
    /* p1: s0 frags rows 64-127, stage next B-s0 */                 \
    READ_F(af2, wm + 64 + lr, &AsL[bR][0][0]);                      \
    READ_F(af3, wm + 96 + lr, &AsL[bR][0][0]);                      \
    STAGE_U(qw, srcB, &BsL[bS][0][0], (knext));                     \
    __builtin_amdgcn_s_barrier();                                   \
    MFMA4(af2, af3, 2, 3);                                          \
    asm volatile("s_waitcnt vmcnt(4)" ::: "memory");                \
    __builtin_amdgcn_s_barrier();                                   \
    /* p2: s1 frags rows 0-63, stage next A-s1 */                   \
    READ_F(af0, wm + lr,      &AsL[bR][1][0]);                      \
    READ_F(af1, wm + 32 + lr, &AsL[bR][1][0]);                      \
    READ_F(bf0, wn + lr,      &BsL[bR][1][0]);                      \
    READ_F(bf1, wn + 32 + lr, &BsL[bR][1][0]);                      \
    STAGE_U(qx, srcA, &AsL[bS][1][0], (knext) + 64);                \
    __builtin_amdgcn_s_barrier();                                   \
    MFMA4(af0, af1, 0, 1);                                          \
    __builtin_amdgcn_s_barrier();                                   \
    /* p3: s1 frags rows 64-127, stage next B-s1 */                 \
    READ_F(af2, wm + 64 + lr, &AsL[bR][1][0]);                      \
    READ_F(af3, wm + 96 + lr, &AsL[bR][1][0]);                      \
    STAGE_U(qw, srcB, &BsL[bS][1][0], (knext) + 64);                \
    __builtin_amdgcn_s_barrier();                                   \
    MFMA4(af2, af3, 2, 3);                                          \
    asm volatile("s_waitcnt vmcnt(4)" ::: "memory");                \
    __builtin_amdgcn_s_barrier();                                   \
} while (0)

    // prologue: stage K-tile 0 (4 units), wait A-s0/B-s0, keep A-s1/B-s1 in flight
    STAGE_U(qx, srcA, &AsL[0][0][0], 0);
    STAGE_U(qw, srcB, &BsL[0][0][0], 0);
    STAGE_U(qx, srcA, &AsL[0][1][0], 64);
    STAGE_U(qw, srcB, &BsL[0][1][0], 64);
    asm volatile("s_waitcnt vmcnt(4)" ::: "memory");
    __builtin_amdgcn_s_barrier();

#pragma unroll 1
    for (int kt = 0; kt < 32; kt += 2) {
        KTILE(0, 1, (kt + 1) * 128);
        KTILE(1, 0, ((kt + 2) & 31) * 128);
    }

    // epilogue: D 32x32 tile: col = lane&31, row = (reg&3) + 8*(reg>>2) + 4*(lane>>5)
    const float wsc = fmaxf(__uint_as_float(*wmaxbits) / FP8MAX, 1e-12f);
#pragma unroll
    for (int i = 0; i < 4; i++) {
#pragma unroll
        for (int reg = 0; reg < 16; reg++) {
            const int row = (reg & 3) + 8 * (reg >> 2) + 4 * lh;
            const int m = m0 + wm + i * 32 + row;
            const float sv = srow[m] * wsc;
            float* orow = out + (size_t)m * HD + n0 + wn + lr;
#pragma unroll
            for (int j = 0; j < 2; j++)
                orow[j * 32] = acc[i][j][reg] * sv;
        }
    }
#undef KTILE
#undef MFMA4
#undef MFMA1
#undef READ_F
#undef STAGE_U
}

// ---------------- launch ----------------
extern "C" void kernel_launch(void* const* d_in, const int* in_sizes, int n_in,
                              void* d_out, int out_size, void* d_ws, size_t ws_size,
                              hipStream_t stream) {
    const float* x   = (const float*)d_in[0];
    const float* nw0 = (const float*)d_in[1];
    const float* nw1 = (const float*)d_in[2];
    const float* nw2 = (const float*)d_in[3];
    const float* nw3 = (const float*)d_in[4];
    const float* W0  = (const float*)d_in[5];
    const float* W1  = (const float*)d_in[6];
    const float* W2  = (const float*)d_in[7];
    float* out = (float*)d_out;

    char* ws = (char*)d_ws;
    const size_t MB = 1024 * 1024;
    float* x2 = out;                       // x2 buffer lives in d_out

    const bool overlap = ws_size >= 118 * MB;

    if (overlap) {
        float*    resid = (float*)(ws);                    // 64 MiB
        uint32_t* qx    = (uint32_t*)(ws + 64 * MB);       // 16 MiB
        uint32_t* qwA   = (uint32_t*)(ws + 80 * MB);       // 16 MiB
        uint32_t* qwB   = (uint32_t*)(ws + 96 * MB);       // 16 MiB
        float*    srow  = (float*)(ws + 112 * MB);         // 16 KiB
        uint32_t* wmax  = (uint32_t*)(ws + 112 * MB + 16384);

        hipMemsetAsync(wmax, 0, 12, stream);
        hipLaunchKernelGGL(w_absmax, dim3(1024, 1, 3), dim3(256), 0, stream, W0, W1, W2, wmax);

        // relu+rms+quant rows, merged with W0 quantization
        hipLaunchKernelGGL(fused_rms, dim3(8192), dim3(256), 0, stream,
                           x, (const float*)nullptr, resid, nw0, qx, srow, (float*)nullptr, 0,
                           W0, wmax + 0, qwA);
        hipLaunchKernelGGL(gemm_fp8mx, dim3(16, 16), dim3(512), 0, stream,
                           (const uint8_t*)qx, (const uint8_t*)qwA, srow, wmax + 0, x2);
        // add+rms+quant, merged with W1 quantization -> qwB
        hipLaunchKernelGGL(fused_rms, dim3(8192), dim3(256), 0, stream,
                           x2, (const float*)resid, resid, nw1, qx, srow, (float*)nullptr, 1,
                           W1, wmax + 1, qwB);
        hipLaunchKernelGGL(gemm_fp8mx, dim3(16, 16), dim3(512), 0, stream,
                           (const uint8_t*)qx, (const uint8_t*)qwB, srow, wmax + 1, x2);
        // add+rms+quant, merged with W2 quantization -> qwA
        hipLaunchKernelGGL(fused_rms, dim3(8192), dim3(256), 0, stream,
                           x2, (const float*)resid, resid, nw2, qx, srow, (float*)nullptr, 1,
                           W2, wmax + 2, qwA);
        hipLaunchKernelGGL(gemm_fp8mx, dim3(16, 16), dim3(512), 0, stream,
                           (const uint8_t*)qx, (const uint8_t*)qwA, srow, wmax + 2, x2);
        hipLaunchKernelGGL(fused_rms, dim3(4096), dim3(256), 0, stream,
                           x2, (const float*)resid, (float*)nullptr, nw3,
                           (uint32_t*)nullptr, (float*)nullptr, out, 2,
                           (const float*)nullptr, (const uint32_t*)nullptr, (uint32_t*)nullptr);
    } else {
        // sequential fallback (single qw buffer)
        float*    resid = (float*)(ws);
        uint32_t* qx    = (uint32_t*)(ws + 64 * MB);
        uint32_t* qw    = (uint32_t*)(ws + 80 * MB);
        float*    srow  = (float*)(ws + 96 * MB);
        uint32_t* wmax  = (uint32_t*)(ws + 96 * MB + 16384);

        hipMemsetAsync(wmax, 0, 12, stream);
        hipLaunchKernelGGL(w_absmax, dim3(1024, 1, 3), dim3(256), 0, stream, W0, W1, W2, wmax);
        hipLaunchKernelGGL(fused_rms, dim3(4096), dim3(256), 0, stream,
                           x, (const float*)nullptr, resid, nw0, qx, srow, (float*)nullptr, 0,
                           (const float*)nullptr, (const uint32_t*)nullptr, (uint32_t*)nullptr);
        const float* Ws[3]  = {W0, W1, W2};
        const float* nws[3] = {nw1, nw2, nw3};
        for (int l = 0; l < 3; l++) {
            hipLaunchKernelGGL(w_quant, dim3(HD * HD / 4 / 256), dim3(256), 0, stream,
                               Ws[l], wmax + l, qw);
            hipLaunchKernelGGL(gemm_fp8mx, dim3(16, 16), dim3(512), 0, stream,
                               (const uint8_t*)qx, (const uint8_t*)qw, srow, wmax + l, x2);
            if (l < 2) {
                hipLaunchKernelGGL(fused_rms, dim3(4096), dim3(256), 0, stream,
                                   x2, (const float*)resid, resid, nws[l], qx, srow,
                                   (float*)nullptr, 1,
                                   (const float*)nullptr, (const uint32_t*)nullptr, (uint32_t*)nullptr);
            } else {
                hipLaunchKernelGGL(fused_rms, dim3(4096), dim3(256), 0, stream,
                                   x2, (const float*)resid, (float*)nullptr, nws[l],
                                   (uint32_t*)nullptr, (float*)nullptr, out, 2,
                                   (const float*)nullptr, (const uint32_t*)nullptr, (uint32_t*)nullptr);
            }
        }
    }
}